// Round 7
// baseline (12022.515 us; speedup 1.0000x reference)
//
#include <hip/hip_runtime.h>

#define FPS_N 32768
#define FPS_M 2048
#define FPS_B 16
#define BLK_PER_B 8
#define FPS_T 512
#define PTS (FPS_N / BLK_PER_B)   // 4096 points per block
#define PPT (PTS / FPS_T)         // 8 points per thread
#define NWAVE (FPS_T / 64)        // 8 waves

typedef unsigned long long ull;

// FPS split 8 ways per batch, cooperative launch (co-resident by construction).
// Round-6 lesson: scan is ~800 cyc/step but the exchange protocol cost ~8k:
// release store = 2 serialized LLC round trips, acquire-per-poll-iter L1
// invalidates, s_sleep quantization, 2nd barrier + LDS broadcast.
// Round-7 protocol: SELF-VALIDATING WORDS. Each block publishes 4 relaxed
// 64-bit agent-scope words, each embedding the step tag in its low 12 bits:
//   wX=(x<<12)|tag  wY=(y<<12)|tag  wZ=(z<<12)|tag
//   wD=(dist<<32)|(idx<<12)|tag      (tag = s+1 <= 2047; ws 0xAA poison field
//                                     = 0xAAA = 2730 never matches)
// -> no release fence (4 stores fly concurrently, ~1 LLC trip to visibility),
// no acquire fence (64-bit atomicity keeps tag+payload consistent; no
// cross-word ordering needed). Parity double-buffer (slot reused at s+2)
// keeps reuse race-free: publishing s+2 requires having consumed all s+1
// payloads, which requires every peer consumed s.
// ALL waves poll (lanes 0..31 <-> 8 slots x 4 words, contiguous 256 B),
// assemble/reduce/broadcast via shfl -> ONE __syncthreads per step, no LDS
// winner broadcast. XCD swizzle: b=blk%16, j=blk/16 puts a batch's 8 blocks
// on one XCD under round-robin dispatch (perf heuristic only).
// Numerics bit-exact vs numpy: contract off, (dx*dx+dy*dy)+dz*dz order,
// strict > / lowest-global-index ties == np.argmax first occurrence.
__global__ __launch_bounds__(FPS_T) void fps_kernel(const float* __restrict__ pts,
                                                    float* __restrict__ out,
                                                    ull* __restrict__ ws) {
#pragma clang fp contract(off)
    __shared__ float4 sc[PTS];          // 64 KiB coords
    __shared__ float red_d[2][NWAVE];
    __shared__ int   red_i[2][NWAVE];

    const int blk = blockIdx.x;
    const int b = blk & 15;             // batch   (same-batch blocks: blk%8 equal)
    const int j = blk >> 4;             // block-within-batch 0..7
    const int tid = threadIdx.x;
    const int lane = tid & 63;
    const float* __restrict__ X = pts + (size_t)b * 3 * FPS_N;
    const float* __restrict__ Y = X + FPS_N;
    const float* __restrict__ Z = Y + FPS_N;
    const int off = j * PTS;
    float* __restrict__ outb = out + (size_t)b * 3 * FPS_M;
    ull* __restrict__ wsb = ws + (size_t)b * 64;   // 2 parities x 8 slots x 4 words

    // one-time stage: this block's 4096 coords -> LDS
    for (int q = tid; q < PTS; q += FPS_T)
        sc[q] = make_float4(X[off + q], Y[off + q], Z[off + q], 0.0f);

    float dist[PPT];
#pragma unroll
    for (int k = 0; k < PPT; ++k) dist[k] = 1e10f;

    float lx = X[0], ly = Y[0], lz = Z[0];   // first selection = index 0
    __syncthreads();

    for (int s = 0; s < FPS_M; ++s) {
        if (j == 0 && tid == 0) {            // emit current selection's coords
            outb[s] = lx;
            outb[FPS_M + s] = ly;
            outb[2 * FPS_M + s] = lz;
        }
        if (s == FPS_M - 1) break;           // last scan unused by output

        // ---- scan own 4096 points: dist update (regs) + local argmax ----
        float bd = -1.0f;
        int bi = 0;
#pragma unroll
        for (int k = 0; k < PPT; ++k) {
            const int q = k * FPS_T + tid;
            float4 c = sc[q];                            // ds_read_b128
            float dx = c.x - lx, dy = c.y - ly, dz = c.z - lz;
            float d = (dx * dx + dy * dy) + dz * dz;     // numpy op order, no fma
            float nd = d < dist[k] ? d : dist[k];
            dist[k] = nd;
            if (nd > bd) { bd = nd; bi = q; }            // strict >: lowest idx
        }
#pragma unroll
        for (int o = 32; o > 0; o >>= 1) {               // wave argmax reduce
            float od = __shfl_down(bd, o);
            int   oi = __shfl_down(bi, o);
            if (od > bd || (od == bd && oi < bi)) { bd = od; bi = oi; }
        }
        const int par = s & 1;
        if (lane == 0) { red_d[par][tid >> 6] = bd; red_i[par][tid >> 6] = bi; }
        __syncthreads();                                 // the ONLY barrier per step

        const unsigned tag = (unsigned)(s + 1);

        // ---- wave 0: reduce 8 wave-partials, lane 0 publishes 4 tagged words
        if (tid < 64) {
            float d8 = (lane < NWAVE) ? red_d[par][lane] : -1.0f;
            int   i8 = (lane < NWAVE) ? red_i[par][lane] : 0x7fffffff;
#pragma unroll
            for (int o = 4; o > 0; o >>= 1) {
                float od = __shfl_down(d8, o);
                int   oi = __shfl_down(i8, o);
                if (od > d8 || (od == d8 && oi < i8)) { d8 = od; i8 = oi; }
            }
            if (lane == 0) {
                float4 c = sc[i8];
                const ull g = (ull)(unsigned)(off + i8); // batch-global idx < 32768
                ull* slot = wsb + par * 32 + j * 4;
                ull wx = ((ull)__float_as_uint(c.x) << 12) | tag;
                ull wy = ((ull)__float_as_uint(c.y) << 12) | tag;
                ull wz = ((ull)__float_as_uint(c.z) << 12) | tag;
                ull wd = ((ull)__float_as_uint(d8) << 32) | (g << 12) | tag;
                // relaxed: no fences, all 4 stores in flight concurrently
                __hip_atomic_store(slot + 0, wx, __ATOMIC_RELAXED, __HIP_MEMORY_SCOPE_AGENT);
                __hip_atomic_store(slot + 1, wy, __ATOMIC_RELAXED, __HIP_MEMORY_SCOPE_AGENT);
                __hip_atomic_store(slot + 2, wz, __ATOMIC_RELAXED, __HIP_MEMORY_SCOPE_AGENT);
                __hip_atomic_store(slot + 3, wd, __ATOMIC_RELAXED, __HIP_MEMORY_SCOPE_AGENT);
            }
        }

        // ---- every wave polls all 8 slots (lanes 0-31: one word each) ----
        ull val = 0;
        bool ok = (lane >= 32);
        ull* pa = wsb + par * 32 + lane;                 // contiguous 256 B
        for (int it = 0; it < (1 << 25); ++it) {
            if (!ok) {
                val = __hip_atomic_load(pa, __ATOMIC_RELAXED, __HIP_MEMORY_SCOPE_AGENT);
                ok = ((unsigned)(val & 0xFFFull) == tag);
            }
            if (__all(ok)) break;
        }

        // assemble slot payloads into lanes 0-7 via shfl
        const int base4 = (lane & 7) << 2;
        ull vx = __shfl(val, base4 + 0);
        ull vy = __shfl(val, base4 + 1);
        ull vz = __shfl(val, base4 + 2);
        ull vd = __shfl(val, base4 + 3);
        float pd, px, py, pz;
        int pidx;
        if (lane < 8) {
            pd   = __uint_as_float((unsigned)(vd >> 32));
            pidx = (int)((vd >> 12) & 0x7FFFull);
            px   = __uint_as_float((unsigned)(vx >> 12));
            py   = __uint_as_float((unsigned)(vy >> 12));
            pz   = __uint_as_float((unsigned)(vz >> 12));
        } else { pd = -1.0f; pidx = 0x7fffffff; px = py = pz = 0.0f; }
        // reduce 8 block partials (coords ride along), ties -> lowest global idx
#pragma unroll
        for (int o = 4; o > 0; o >>= 1) {
            float od = __shfl_down(pd, o);
            int   oi = __shfl_down(pidx, o);
            float ox = __shfl_down(px, o);
            float oy = __shfl_down(py, o);
            float oz = __shfl_down(pz, o);
            if (od > pd || (od == pd && oi < pidx)) {
                pd = od; pidx = oi; px = ox; py = oy; pz = oz;
            }
        }
        lx = __shfl(px, 0);                              // broadcast winner coords
        ly = __shfl(py, 0);
        lz = __shfl(pz, 0);
    }
}

extern "C" void kernel_launch(void* const* d_in, const int* in_sizes, int n_in,
                              void* d_out, int out_size, void* d_ws, size_t ws_size,
                              hipStream_t stream) {
    const float* pts = (const float*)d_in[0];   // [16, 3, 32768] fp32
    float* out = (float*)d_out;                 // [16, 3, 2048] fp32
    ull* ws = (ull*)d_ws;                       // 16 batches x 64 words = 8 KB used
    void* args[] = { (void*)&pts, (void*)&out, (void*)&ws };
    hipLaunchCooperativeKernel((const void*)fps_kernel,
                               dim3(FPS_B * BLK_PER_B), dim3(FPS_T),
                               args, 0, stream);
}

// Round 8
// 5178.047 us; speedup vs baseline: 2.3218x; 2.3218x over previous
//
#include <hip/hip_runtime.h>

#define FPS_N 32768
#define FPS_M 2048
#define FPS_B 16
#define BLK_PER_B 8
#define FPS_T 512
#define PTS (FPS_N / BLK_PER_B)   // 4096 points per block
#define PPT (PTS / FPS_T)         // 8 points per thread
#define NWAVE (FPS_T / 64)        // 8 waves

typedef unsigned long long ull;

// FPS split 8 ways per batch, cooperative launch (co-resident by construction).
// Round 6 (3-word release/acquire, 1-wave poll + s_sleep): 7.8 ms. Round 7
// (4-word relaxed, ALL-wave 4-line poll): 12.0 ms -- poll storm queues ahead
// of publishers at the coherent point. Round 8 minimizes coherent traffic:
//   PUBLISH = ONE relaxed agent-scope 64-bit word per block per step:
//     (dist_bits<<32) | ((32767-idx)<<17) | tag     tag = s+1 (12 bits)
//   dist >= 0 -> IEEE bits uint-monotone; inverted idx -> plain u64 MAX is
//   exactly argmax with lowest-global-index tie-break (np.argmax semantics).
//   8 slots/batch = one 64-B line; parity double-buffered (reuse at s+2 is
//   provably post-consumption); 0xAA ws poison -> tag field 0xAAA never
//   matches a real tag (<= 2047).
//   POLL = wave 0 only, lanes 0-7, one line, relaxed loads (self-throttled
//   by LLC latency). No fences anywhere: single-word atomicity carries the
//   whole payload, no cross-word ordering exists.
//   Winner COORDS come from the read-only input X/Y/Z[idx] via normal
//   L2-cached loads (384 KiB batch slice is L2-resident; no coherence needed
//   on immutable data) -- cheaper than shipping coords through the LLC.
// Numerics bit-exact vs numpy: contract off, (dx*dx+dy*dy)+dz*dz order,
// strict > / lowest-index ties.
__global__ __launch_bounds__(FPS_T) void fps_kernel(const float* __restrict__ pts,
                                                    float* __restrict__ out,
                                                    ull* __restrict__ ws) {
#pragma clang fp contract(off)
    __shared__ float4 sc[PTS];          // 64 KiB coords
    __shared__ float red_d[2][NWAVE];
    __shared__ int   red_i[2][NWAVE];
    __shared__ float swin[3];

    const int blk = blockIdx.x;
    const int b = blk & 15;             // batch; same-batch blocks share blk%8
    const int j = blk >> 4;             // block-within-batch 0..7  (XCD swizzle)
    const int tid = threadIdx.x;
    const int lane = tid & 63;
    const float* __restrict__ X = pts + (size_t)b * 3 * FPS_N;
    const float* __restrict__ Y = X + FPS_N;
    const float* __restrict__ Z = Y + FPS_N;
    const int off = j * PTS;
    float* __restrict__ outb = out + (size_t)b * 3 * FPS_M;
    ull* __restrict__ wsb = ws + (size_t)b * 16;  // 2 parities x 8 slots (2x64B)

    // one-time stage: this block's 4096 coords -> LDS
    for (int q = tid; q < PTS; q += FPS_T)
        sc[q] = make_float4(X[off + q], Y[off + q], Z[off + q], 0.0f);

    float dist[PPT];
#pragma unroll
    for (int k = 0; k < PPT; ++k) dist[k] = 1e10f;

    float lx = X[0], ly = Y[0], lz = Z[0];   // first selection = index 0
    __syncthreads();

    for (int s = 0; s < FPS_M; ++s) {
        if (j == 0 && tid == 0) {            // emit current selection's coords
            outb[s] = lx;
            outb[FPS_M + s] = ly;
            outb[2 * FPS_M + s] = lz;
        }
        if (s == FPS_M - 1) break;           // last scan unused by output

        // ---- scan own 4096 points: reg dist update + local argmax ----
        float bd = -1.0f;
        int bi = 0;
#pragma unroll
        for (int k = 0; k < PPT; ++k) {
            const int q = k * FPS_T + tid;
            float4 c = sc[q];                            // ds_read_b128
            float dx = c.x - lx, dy = c.y - ly, dz = c.z - lz;
            float d = (dx * dx + dy * dy) + dz * dz;     // numpy op order, no fma
            float nd = d < dist[k] ? d : dist[k];
            dist[k] = nd;
            if (nd > bd) { bd = nd; bi = q; }            // strict >: lowest idx
        }
#pragma unroll
        for (int o = 32; o > 0; o >>= 1) {               // wave argmax reduce
            float od = __shfl_down(bd, o);
            int   oi = __shfl_down(bi, o);
            if (od > bd || (od == bd && oi < bi)) { bd = od; bi = oi; }
        }
        const int par = s & 1;
        if (lane == 0) { red_d[par][tid >> 6] = bd; red_i[par][tid >> 6] = bi; }
        __syncthreads();

        // ---- wave 0: cross-wave reduce, publish 1 word, poll 1 line ----
        if (tid < 64) {
            float d8 = (lane < NWAVE) ? red_d[par][lane] : -1.0f;
            int   i8 = (lane < NWAVE) ? red_i[par][lane] : 0x7fffffff;
#pragma unroll
            for (int o = 4; o > 0; o >>= 1) {
                float od = __shfl_down(d8, o);
                int   oi = __shfl_down(i8, o);
                if (od > d8 || (od == d8 && oi < i8)) { d8 = od; i8 = oi; }
            }
            const unsigned tag = (unsigned)(s + 1);
            ull* line = wsb + par * 8;                   // one 64-B line
            if (lane == 0) {
                const unsigned gidx = (unsigned)(off + i8);      // 0..32767
                ull w = ((ull)__float_as_uint(d8) << 32)
                      | ((ull)(32767u - gidx) << 17)
                      | (ull)tag;
                __hip_atomic_store(line + j, w, __ATOMIC_RELAXED,
                                   __HIP_MEMORY_SCOPE_AGENT);
            }
            // lanes 0-7 poll (relaxed; load latency self-throttles the spin)
            ull v = 0;
            bool ok = (lane >= 8);
            for (int it = 0; it < (1 << 25); ++it) {
                if (!ok) {
                    v = __hip_atomic_load(line + lane, __ATOMIC_RELAXED,
                                          __HIP_MEMORY_SCOPE_AGENT);
                    ok = ((unsigned)(v & 0xFFFull) == tag);
                }
                if (__all(ok)) break;
            }
            // u64 max over lanes 0-7 == argmax w/ lowest-index tie-break
            if (lane >= 8) v = 0;
#pragma unroll
            for (int o = 4; o > 0; o >>= 1) {
                ull ov = __shfl_down(v, o);
                if (ov > v) v = ov;
            }
            int widx = 32767 - (int)((v >> 17) & 0x7FFFull);
            widx = __shfl(widx, 0);                      // broadcast from lane 0
            // winner coords from immutable input (L2-resident, no coherence)
            if (lane == 0)      swin[0] = X[widx];
            else if (lane == 1) swin[1] = Y[widx];
            else if (lane == 2) swin[2] = Z[widx];
        }
        __syncthreads();
        lx = swin[0];
        ly = swin[1];
        lz = swin[2];
    }
}

extern "C" void kernel_launch(void* const* d_in, const int* in_sizes, int n_in,
                              void* d_out, int out_size, void* d_ws, size_t ws_size,
                              hipStream_t stream) {
    const float* pts = (const float*)d_in[0];   // [16, 3, 32768] fp32
    float* out = (float*)d_out;                 // [16, 3, 2048] fp32
    ull* ws = (ull*)d_ws;                       // 16 batches x 16 words = 2 KB
    void* args[] = { (void*)&pts, (void*)&out, (void*)&ws };
    hipLaunchCooperativeKernel((const void*)fps_kernel,
                               dim3(FPS_B * BLK_PER_B), dim3(FPS_T),
                               args, 0, stream);
}

// Round 9
// 4340.002 us; speedup vs baseline: 2.7702x; 1.1931x over previous
//
#include <hip/hip_runtime.h>

#define FPS_N 32768
#define FPS_M 2048
#define FPS_B 16
#define BLK_PER_B 8
#define FPS_T 576                 // 9 waves: wave 0 = comm, waves 1-8 = scan
#define SCT 512                   // scan threads
#define PTS (FPS_N / BLK_PER_B)   // 4096 points per block
#define PPT (PTS / SCT)           // 8 points per scan thread

typedef unsigned long long ull;

// FPS split 8 ways per batch, cooperative launch. Round-8 (5.18 ms) step was
// ~6k cyc: consensus RT ~2.1k is LLC physics, but ~1.5k was protocol around
// it (2 full-block barriers, dual-value shfl reduces, all-wave broadcast).
// Round 9: WAVE SPECIALIZATION, zero barriers in the step loop.
//   wave 0 (comm): spin 8 tagged LDS partials -> u64-max -> publish 1 relaxed
//     agent word -> poll 1 LLC line -> u64-max -> fetch winner coords (lanes
//     0-2, L2, immutable input) -> post coords + release tag to LDS -> also
//     writes the output row (off the scan path).
//   waves 1-8 (scan): scan 8 pts/thread from LDS float4, pack wave-best as
//     the SAME self-validating u64 (dist<<32 | (32767-gidx)<<17 | tag) ->
//     6-shfl u64 max (vs 12-shfl dual reduce) -> tagged LDS slot -> spin on
//     LDS winner tag (broadcast read, ~free) -> next scan.
// u64 max == np.argmax first-occurrence: dist >= 0 so IEEE bits are
// uint-monotone; inverted global index breaks ties toward lowest index.
// Tag safety: tags are monotone 1..2047. LDS slots need no parity: partial(s)
// is consumed by comm before winner(s) is posted, and a scan wave can only
// write partial(s+1) after seeing winner(s). LLC slots keep parity (slot s
// reused at s+2, provably post-consumption). ws poison 0xAA -> tag field
// 0xAAA=2730 never matches; LDS slots are zero-init'd before the loop.
// Numerics bit-exact vs numpy: contract off, (dx*dx+dy*dy)+dz*dz, no fma.
__global__ __launch_bounds__(FPS_T) void fps_kernel(const float* __restrict__ pts,
                                                    float* __restrict__ out,
                                                    ull* __restrict__ ws) {
#pragma clang fp contract(off)
    __shared__ float4 sc[PTS];          // 64 KiB coords
    __shared__ ull part[8];             // tagged per-scan-wave partials
    __shared__ float swx, swy, swz;     // winner coords
    __shared__ unsigned swtag;          // winner tag (release/acquire)

    const int blk = blockIdx.x;
    const int b = blk & 15;             // batch; same-batch blocks share XCD
    const int j = blk >> 4;             // block-within-batch 0..7
    const int tid = threadIdx.x;
    const float* __restrict__ X = pts + (size_t)b * 3 * FPS_N;
    const float* __restrict__ Y = X + FPS_N;
    const float* __restrict__ Z = Y + FPS_N;
    const int off = j * PTS;
    float* __restrict__ outb = out + (size_t)b * 3 * FPS_M;
    ull* __restrict__ wsb = ws + (size_t)b * 16;  // 2 parities x 8 slots

    for (int q = tid; q < PTS; q += FPS_T)        // one-time coord stage
        sc[q] = make_float4(X[off + q], Y[off + q], Z[off + q], 0.0f);
    if (tid < 8) part[tid] = 0;                   // kill stale-LDS tag aliasing
    if (tid == 8) swtag = 0;
    __syncthreads();                              // the only barrier (pre-loop)

    if (tid < 64) {
        // ================= comm wave =================
        const int lane = tid;
        if (j == 0 && lane == 0) {                // selection 0 = point 0
            outb[0]         = X[0];
            outb[FPS_M]     = Y[0];
            outb[2 * FPS_M] = Z[0];
        }
        for (int s = 1; s < FPS_M; ++s) {
            const unsigned tag = (unsigned)s;
            // gather 8 tagged partials from LDS (trickle-in pickup)
            ull pv = 0;
            bool ok = (lane >= 8);
            for (int it = 0; it < (1 << 25); ++it) {
                if (!ok) {
                    pv = __hip_atomic_load(&part[lane], __ATOMIC_RELAXED,
                                           __HIP_MEMORY_SCOPE_WORKGROUP);
                    ok = ((unsigned)(pv & 0xFFFull) == tag);
                }
                if (__all(ok)) break;
            }
            ull v = (lane < 8) ? pv : 0;          // real words > 0 (tag bits)
#pragma unroll
            for (int o = 4; o > 0; o >>= 1) {     // block-best in lane 0
                ull ov = __shfl_down(v, o);
                if (ov > v) v = ov;
            }
            ull* line = wsb + (s & 1) * 8;        // parity-buffered 64-B line
            if (lane == 0)
                __hip_atomic_store(line + j, v, __ATOMIC_RELAXED,
                                   __HIP_MEMORY_SCOPE_AGENT);
            // poll the batch line (lanes 0-7), relaxed, self-throttled
            ull r = 0;
            ok = (lane >= 8);
            for (int it = 0; it < (1 << 25); ++it) {
                if (!ok) {
                    r = __hip_atomic_load(line + lane, __ATOMIC_RELAXED,
                                          __HIP_MEMORY_SCOPE_AGENT);
                    ok = ((unsigned)(r & 0xFFFull) == tag);
                }
                if (__all(ok)) break;
            }
            if (lane >= 8) r = 0;
#pragma unroll
            for (int o = 4; o > 0; o >>= 1) {     // global winner in lane 0
                ull orr = __shfl_down(r, o);
                if (orr > r) r = orr;
            }
            int widx = 32767 - (int)((r >> 17) & 0x7FFFull);
            widx = __shfl(widx, 0);
            // winner coords from immutable input (L2-resident), lanes 0-2
            float cv = 0.0f;
            if (lane == 0)      cv = X[widx];
            else if (lane == 1) cv = Y[widx];
            else if (lane == 2) cv = Z[widx];
            if (lane == 0)      swx = cv;
            else if (lane == 1) swy = cv;
            else if (lane == 2) swz = cv;
            // release tag: wave-wide lgkmcnt drain orders the coord writes
            if (lane == 0)
                __hip_atomic_store(&swtag, tag, __ATOMIC_RELEASE,
                                   __HIP_MEMORY_SCOPE_WORKGROUP);
            if (j == 0 && lane < 3)               // output row s (off scan path)
                outb[(size_t)lane * FPS_M + s] = cv;
        }
    } else {
        // ================= scan waves =================
        const int st = tid - 64;                  // 0..511
        const int wv = (tid >> 6) - 1;            // scan wave 0..7
        const int lane = tid & 63;
        float dist[PPT];
#pragma unroll
        for (int k = 0; k < PPT; ++k) dist[k] = 1e10f;
        float lx = X[0], ly = Y[0], lz = Z[0];    // first selection = index 0

        for (int s = 1; s < FPS_M; ++s) {
            const unsigned tag = (unsigned)s;
            float bd = -1.0f;
            int bi = 0;
#pragma unroll
            for (int k = 0; k < PPT; ++k) {
                const int q = k * SCT + st;
                float4 c = sc[q];                            // ds_read_b128
                float dx = c.x - lx, dy = c.y - ly, dz = c.z - lz;
                float d = (dx * dx + dy * dy) + dz * dz;     // numpy order
                float nd = d < dist[k] ? d : dist[k];
                dist[k] = nd;
                if (nd > bd) { bd = nd; bi = q; }            // strict >
            }
            // pack once, then 6-shfl u64-max wave reduce
            ull w = ((ull)__float_as_uint(bd) << 32)
                  | ((ull)(32767u - (unsigned)(off + bi)) << 17)
                  | (ull)tag;
#pragma unroll
            for (int o = 32; o > 0; o >>= 1) {
                ull ow = __shfl_down(w, o);
                if (ow > w) w = ow;
            }
            if (lane == 0)
                __hip_atomic_store(&part[wv], w, __ATOMIC_RELAXED,
                                   __HIP_MEMORY_SCOPE_WORKGROUP);
            // wait for winner(s): LDS broadcast spin (acquire orders coord reads)
            for (int it = 0; it < (1 << 25); ++it) {
                unsigned t = __hip_atomic_load(&swtag, __ATOMIC_ACQUIRE,
                                               __HIP_MEMORY_SCOPE_WORKGROUP);
                if (t == tag) break;
            }
            lx = swx;
            ly = swy;
            lz = swz;
        }
    }
}

extern "C" void kernel_launch(void* const* d_in, const int* in_sizes, int n_in,
                              void* d_out, int out_size, void* d_ws, size_t ws_size,
                              hipStream_t stream) {
    const float* pts = (const float*)d_in[0];   // [16, 3, 32768] fp32
    float* out = (float*)d_out;                 // [16, 3, 2048] fp32
    ull* ws = (ull*)d_ws;                       // 16 batches x 16 words = 2 KB
    void* args[] = { (void*)&pts, (void*)&out, (void*)&ws };
    hipLaunchCooperativeKernel((const void*)fps_kernel,
                               dim3(FPS_B * BLK_PER_B), dim3(FPS_T),
                               args, 0, stream);
}